// Round 4
// baseline (10146.360 us; speedup 1.0000x reference)
//
#include <hip/hip_runtime.h>
#include <hip/hip_cooperative_groups.h>
#include <math.h>

namespace cg = cooperative_groups;

#define VOCAB 32000
#define EMB   256
#define HID   512
#define NB    32
#define TT    128
#define TM1   127
#define SS    128
#define NROWS (TM1*NB)     // 4064
#define NT128 250          // 32000/128
#define NLSTM 128          // lstm blocks in scan

// ---- workspace layout (float32 offsets) ----
#define OFF_ENCW 0          // bf16 [32][128][512] enc@attnW_enc^T + attnb
#define OFF_AWQT 1048576    // f32  [512][512]  attnW[:, :512] transposed
#define OFF_H0B  1310720    // bf16 ring [8][32][512] h0
#define OFF_H1B  1376256    // bf16 ring [2][32][512] h1
#define OFF_C0   1392640    // f32  [512][32]
#define OFF_C1   1409024    // f32  [512][32]
#define OFF_G0X  1425408    // bf16 [127][2048][32]  emb@Wih0^T + biases
#define OFF_CATB 5586944    // bf16 [4096][1024]  (h1 history ∥ weighted)
#define OFF_PART 7684096    // float2 [4096][250]; ints [0]=c0 [32]=c1 during scan
#define OFF_NLL  9732096
#define OFF_CNT  9736160
// end 9,740,224 f32 = 38.96 MB (ws proven >= 41.9 MB in round 0)

typedef __attribute__((ext_vector_type(8))) short short8;
typedef __attribute__((ext_vector_type(4))) float f32x4;

__device__ __forceinline__ float sigm(float x){ return 1.f/(1.f + __expf(-x)); }
__device__ __forceinline__ float tanh_f(float x){
    x = fminf(fmaxf(x, -15.f), 15.f);
    float e = __expf(2.f*x);
    return (e-1.f)/(e+1.f);
}
__device__ __forceinline__ unsigned short f2b(float f){
    union{float f; unsigned u;} x{f};
    unsigned r = (x.u + 0x7fff + ((x.u>>16)&1)) >> 16;
    return (unsigned short)r;
}
__device__ __forceinline__ float b2f(unsigned short b){
    union{unsigned u; float f;} x{(unsigned)b<<16};
    return x.f;
}
__device__ __forceinline__ uint4 pack8(const float4 f0, const float4 f1){
    uint4 r;
    r.x = ((unsigned)f2b(f0.x)) | ((unsigned)f2b(f0.y)<<16);
    r.y = ((unsigned)f2b(f0.z)) | ((unsigned)f2b(f0.w)<<16);
    r.z = ((unsigned)f2b(f1.x)) | ((unsigned)f2b(f1.y)<<16);
    r.w = ((unsigned)f2b(f1.z)) | ((unsigned)f2b(f1.w)<<16);
    return r;
}

// ------------------------------------------------------------------ init
__global__ void k_init(const float* __restrict__ hid, const float* __restrict__ cel,
                       float* __restrict__ ws){
    int idx = blockIdx.x*256 + threadIdx.x;
    if (idx < 2*HID*NB){
        int l = idx >> 14, r = idx & 16383;      // r = k*32+b
        int k = r >> 5, b = r & 31;
        float hv = 0.5f*(hid[(2*l)*(NB*HID) + b*HID + k] + hid[(2*l+1)*(NB*HID) + b*HID + k]);
        float cv = 0.5f*(cel[(2*l)*(NB*HID) + b*HID + k] + cel[(2*l+1)*(NB*HID) + b*HID + k]);
        unsigned short* hb = (unsigned short*)(ws + (l==0 ? OFF_H0B : OFF_H1B));
        hb[b*512 + k] = f2b(hv);                 // ring slot 0
        ws[(l==0 ? OFF_C0 : OFF_C1) + k*32 + b] = cv;
    } else {
        int j = idx - 2*HID*NB;
        if (j < 32*1024){                         // zero catb pad rows 4064..4095
            unsigned short* catb = (unsigned short*)(ws + OFF_CATB);
            catb[(size_t)4064*1024 + j] = 0;
        }
        if (j < 2){                               // zero sync counters c0,c1
            ((int*)(ws + OFF_PART))[j*32] = 0;
        }
    }
}

// ------------------------------------------------------------------ prep
__global__ void k_prep(const float* __restrict__ attnW, float* __restrict__ ws){
    int idx = blockIdx.x*256 + threadIdx.x;      // 262144
    int k = idx >> 9, h = idx & 511;
    ws[OFF_AWQT + k*512 + h] = attnW[h*1024 + k];
}

// ---------------------------------------------- encW = enc @ attnW[:,512:]^T + attnb  (bf16)
__global__ void k_encw(const float* __restrict__ enc, const float* __restrict__ attnW,
                       const float* __restrict__ attnb, float* __restrict__ ws){
    __shared__ float As[64][33];
    __shared__ float Bs[64][33];
    int tid = threadIdx.x;
    int nt = blockIdx.x, mt = blockIdx.y;
    int m0 = mt*64, n0 = nt*64;
    int ty = tid >> 4, tx = tid & 15;
    float acc[4][4] = {};
    for (int kk = 0; kk < 16; ++kk){
        int k0 = kk*32;
        #pragma unroll
        for (int i = 0; i < 8; ++i){
            int idx = tid + i*256;
            int r = idx >> 5, k = idx & 31;
            As[r][k] = enc[(m0+r)*HID + k0 + k];
            Bs[r][k] = attnW[(n0+r)*1024 + 512 + k0 + k];
        }
        __syncthreads();
        #pragma unroll
        for (int k = 0; k < 32; ++k){
            float av[4], bv[4];
            #pragma unroll
            for (int i=0;i<4;i++) av[i] = As[ty*4+i][k];
            #pragma unroll
            for (int j=0;j<4;j++) bv[j] = Bs[tx*4+j][k];
            #pragma unroll
            for (int i=0;i<4;i++)
                #pragma unroll
                for (int j=0;j<4;j++) acc[i][j] += av[i]*bv[j];
        }
        __syncthreads();
    }
    unsigned short* encwb = (unsigned short*)(ws + OFF_ENCW);
    #pragma unroll
    for (int i=0;i<4;i++)
      #pragma unroll
      for (int j=0;j<4;j++){
        int m = m0 + ty*4+i, n = n0 + tx*4+j;
        encwb[(size_t)m*512 + n] = f2b(acc[i][j] + attnb[n]);
      }
}

// ------------------------- g0x[t][row][b] = emb[X[b,t]] @ Wih0^T + bih0 + bhh0  (bf16)
__global__ void k_g0x(const int* __restrict__ X, const float* __restrict__ emb,
                      const float* __restrict__ Wih0, const float* __restrict__ bih0,
                      const float* __restrict__ bhh0, float* __restrict__ ws){
    __shared__ float As[64][33];
    __shared__ float Bs[64][33];
    int tid = threadIdx.x;
    int nt = blockIdx.x, mt = blockIdx.y;
    int m0 = mt*64, n0 = nt*64;
    int ty = tid >> 4, tx = tid & 15;
    float acc[4][4] = {};
    for (int kk = 0; kk < 8; ++kk){
        int k0 = kk*32;
        #pragma unroll
        for (int i = 0; i < 8; ++i){
            int idx = tid + i*256;
            int r = idx >> 5, k = idx & 31;
            int m = m0 + r;
            int tok = (m < NROWS) ? X[(m&31)*TT + (m>>5)] : 0;
            As[r][k] = emb[(size_t)tok*EMB + k0 + k];
            Bs[r][k] = Wih0[(n0+r)*EMB + k0 + k];
        }
        __syncthreads();
        #pragma unroll
        for (int k = 0; k < 32; ++k){
            float av[4], bv[4];
            #pragma unroll
            for (int i=0;i<4;i++) av[i] = As[ty*4+i][k];
            #pragma unroll
            for (int j=0;j<4;j++) bv[j] = Bs[tx*4+j][k];
            #pragma unroll
            for (int i=0;i<4;i++)
                #pragma unroll
                for (int j=0;j<4;j++) acc[i][j] += av[i]*bv[j];
        }
        __syncthreads();
    }
    unsigned short* g0xb = (unsigned short*)(ws + OFF_G0X);
    #pragma unroll
    for (int i=0;i<4;i++){
        int m = m0 + ty*4+i;
        if (m >= NROWS) continue;
        int t = m >> 5, b = m & 31;
        #pragma unroll
        for (int j=0;j<4;j++){
            int n = n0 + tx*4+j;
            g0xb[((size_t)t*2048 + n)*32 + b] = f2b(acc[i][j] + bih0[n] + bhh0[n]);
        }
    }
}

// ------------------------------------------------------------------ persistent scan
// 128 lstm blocks (4 units each, L0+L1 weights in LDS) + 32 attn blocks.
// Sync: monotonic agent-scope counters c0 (lstm group barrier per step) and
// c1 (h1/catb publish consumed by attn). attn reads h1 history from catb.
__global__ void __launch_bounds__(512, 1)
k_scan(const float* __restrict__ enc, const float* __restrict__ Whh0,
       const float* __restrict__ Wih1, const float* __restrict__ Whh1,
       const float* __restrict__ bih1, const float* __restrict__ bhh1,
       const float* __restrict__ v, float* ws)
{
    const int blk = blockIdx.x, tid = threadIdx.x;
    __shared__ __align__(16) char smem[59648];
    unsigned short* catb  = (unsigned short*)(ws + OFF_CATB);
    const unsigned short* g0xb  = (const unsigned short*)(ws + OFF_G0X);
    const unsigned short* encwb = (const unsigned short*)(ws + OFF_ENCW);
    unsigned short* h0b = (unsigned short*)(ws + OFF_H0B);   // [8][32][512]
    unsigned short* h1b = (unsigned short*)(ws + OFF_H1B);   // [2][32][512]
    int* c0 = (int*)(ws + OFF_PART);
    int* c1 = (int*)(ws + OFF_PART) + 32;

    if (blk < NLSTM){
        // LDS layout
        unsigned short* Ws0 = (unsigned short*)smem;              // [16][512]  16 KB
        unsigned short* Ws1 = (unsigned short*)(smem + 16384);    // [16][1024] 32 KB
        float* red  = (float*)(smem + 49152);                     // [8][64][4]  8 KB
        float* gbuf = (float*)(smem + 57344);                     // [32][17]  2176 B
        float* bs1  = (float*)(smem + 59520);                     // [16]
        const int u0 = blk*4;
        // ---- stage weights once ----
        if (tid < 256){   // Ws0: rows n = g*4+j of Whh0 (row g*512+u0+j), K=512
            int n = tid >> 4, q = tid & 15;
            int g = n >> 2, j = n & 3;
            const float* src = Whh0 + ((size_t)(g*512 + u0 + j))*512 + q*32;
            #pragma unroll
            for (int c = 0; c < 4; ++c){
                float4 f0 = *(const float4*)(src + c*8);
                float4 f1 = *(const float4*)(src + c*8 + 4);
                int s = q*4 + c;
                *(uint4*)&Ws0[n*512 + ((s ^ (n&7))<<3)] = pack8(f0, f1);
            }
        }
        {   // Ws1: rows n = g*4+j of [Wih1;Whh1] (row g*512+u0+j), K=1024
            int n = tid >> 5, q = tid & 31;
            int g = n >> 2, j = n & 3;
            int grow = g*512 + u0 + j;
            int k0 = q*32;
            const float* src = (k0 < 512) ? (Wih1 + (size_t)grow*512 + k0)
                                          : (Whh1 + (size_t)grow*512 + (k0-512));
            #pragma unroll
            for (int c = 0; c < 4; ++c){
                float4 f0 = *(const float4*)(src + c*8);
                float4 f1 = *(const float4*)(src + c*8 + 4);
                int s = q*4 + c;
                *(uint4*)&Ws1[n*1024 + ((s ^ (n&7))<<3)] = pack8(f0, f1);
            }
        }
        if (tid < 16){
            int g = tid >> 2, j = tid & 3;
            int gr = g*512 + u0 + j;
            bs1[tid] = bih1[gr] + bhh1[gr];
        }
        __syncthreads();

        const int w = tid >> 6, lane = tid & 63;
        const int kg = w & 3, mt = w >> 2;
        const int lr = lane & 15, lg = lane >> 4;

        for (int i = 0; i <= 127; ++i){
            // ---------- part A: lstm0 step i ----------
            if (i <= 126){
                const unsigned short* hsrc = h0b + (i&7)*16384;
                f32x4 acc = {0.f,0.f,0.f,0.f};
                #pragma unroll
                for (int ks = 0; ks < 4; ++ks){
                    int kk = kg*4 + ks;
                    short8 a = *(const short8*)(hsrc + (mt*16+lr)*512 + kk*32 + lg*8);
                    int sl = kk*4 + lg;
                    short8 b0 = *(const short8*)&Ws0[lr*512 + ((sl ^ (lr&7))<<3)];
                    acc = __builtin_amdgcn_mfma_f32_16x16x32_bf16(a, b0, acc, 0,0,0);
                }
                *(f32x4*)&red[(w*64 + lane)*4] = acc;
                __syncthreads();
                {   // combine K-splits: 512 outputs (2mt x 16row x 16b)
                    int reg = tid & 3, ln = (tid>>2) & 63, mtl = tid >> 8;
                    float s = 0.f;
                    #pragma unroll
                    for (int kg2 = 0; kg2 < 4; ++kg2)
                        s += red[((mtl*4+kg2)*64 + ln)*4 + reg];
                    int bb = mtl*16 + (ln>>4)*4 + reg;
                    int nn = ln & 15;
                    gbuf[bb*17 + nn] = s;
                }
                __syncthreads();
                if (tid < 128){
                    int j = tid >> 5, b = tid & 31;
                    int u = u0 + j;
                    const unsigned short* gx = g0xb + (size_t)i*65536;
                    float gi = gbuf[b*17 + 0*4 + j] + b2f(gx[(0*512+u)*32 + b]);
                    float gf = gbuf[b*17 + 1*4 + j] + b2f(gx[(1*512+u)*32 + b]);
                    float gg = gbuf[b*17 + 2*4 + j] + b2f(gx[(2*512+u)*32 + b]);
                    float go = gbuf[b*17 + 3*4 + j] + b2f(gx[(3*512+u)*32 + b]);
                    float c  = ws[OFF_C0 + u*32 + b];
                    float cn = sigm(gf)*c + sigm(gi)*tanh_f(gg);
                    float hn = sigm(go)*tanh_f(cn);
                    ws[OFF_C0 + u*32 + b] = cn;
                    h0b[((i+1)&7)*16384 + b*512 + u] = f2b(hn);
                }
            }
            // ---------- group barrier: publish h0[i+1], await peers ----------
            __threadfence();
            __syncthreads();
            if (tid == 0){
                __hip_atomic_fetch_add(c0, 1, __ATOMIC_RELEASE, __HIP_MEMORY_SCOPE_AGENT);
                while (__hip_atomic_load(c0, __ATOMIC_ACQUIRE, __HIP_MEMORY_SCOPE_AGENT) < NLSTM*(i+1))
                    __builtin_amdgcn_s_sleep(2);
                __threadfence();
            }
            __syncthreads();
            // ---------- part B: lstm1 step i-1 ----------
            if (i >= 1){
                const unsigned short* h0src = h0b + (i&7)*16384;
                const unsigned short* h1src = h1b + ((i-1)&1)*16384;
                f32x4 acc = {0.f,0.f,0.f,0.f};
                #pragma unroll
                for (int ks = 0; ks < 8; ++ks){
                    int kk = kg*8 + ks;
                    const unsigned short* hs = (kk < 16)
                        ? (h0src + (mt*16+lr)*512 + kk*32 + lg*8)
                        : (h1src + (mt*16+lr)*512 + (kk-16)*32 + lg*8);
                    short8 a = *(const short8*)hs;
                    int sl = kk*4 + lg;
                    short8 b0 = *(const short8*)&Ws1[lr*1024 + ((sl ^ (lr&7))<<3)];
                    acc = __builtin_amdgcn_mfma_f32_16x16x32_bf16(a, b0, acc, 0,0,0);
                }
                *(f32x4*)&red[(w*64 + lane)*4] = acc;
                __syncthreads();
                {
                    int reg = tid & 3, ln = (tid>>2) & 63, mtl = tid >> 8;
                    float s = 0.f;
                    #pragma unroll
                    for (int kg2 = 0; kg2 < 4; ++kg2)
                        s += red[((mtl*4+kg2)*64 + ln)*4 + reg];
                    int bb = mtl*16 + (ln>>4)*4 + reg;
                    int nn = ln & 15;
                    gbuf[bb*17 + nn] = s;
                }
                __syncthreads();
                if (tid < 128){
                    int j = tid >> 5, b = tid & 31;
                    int u = u0 + j;
                    float gi = gbuf[b*17 + 0*4 + j] + bs1[0*4 + j];
                    float gf = gbuf[b*17 + 1*4 + j] + bs1[1*4 + j];
                    float gg = gbuf[b*17 + 2*4 + j] + bs1[2*4 + j];
                    float go = gbuf[b*17 + 3*4 + j] + bs1[3*4 + j];
                    float c  = ws[OFF_C1 + u*32 + b];
                    float cn = sigm(gf)*c + sigm(gi)*tanh_f(gg);
                    float hn = sigm(go)*tanh_f(cn);
                    ws[OFF_C1 + u*32 + b] = cn;
                    h1b[(i&1)*16384 + b*512 + u] = f2b(hn);
                    catb[((size_t)((i-1)*32 + b) << 10) + u] = f2b(hn);
                }
            }
            // ---------- publish h1/catb ----------
            __threadfence();
            __syncthreads();
            if (tid == 0)
                __hip_atomic_fetch_add(c1, 1, __ATOMIC_RELEASE, __HIP_MEMORY_SCOPE_AGENT);
        }
    } else {
        // ================= attention: one block per batch =================
        float* h1s  = (float*)smem;           // 512
        float* hqv  = (float*)(smem + 2048);  // 512
        float* attv = (float*)(smem + 4096);  // 128
        float* rbuf = (float*)(smem + 4608);  // 2
        const int b = blk - NLSTM;
        const float* aWqT = ws + OFF_AWQT;
        for (int ta = 0; ta < TM1; ++ta){
            // wait for catb row ta (h1[ta+1]) published at lstm iter ta+1
            if (tid == 0){
                while (__hip_atomic_load(c1, __ATOMIC_ACQUIRE, __HIP_MEMORY_SCOPE_AGENT) < NLSTM*(ta+2))
                    __builtin_amdgcn_s_sleep(2);
                __threadfence();
            }
            __syncthreads();
            h1s[tid] = b2f(catb[((size_t)(ta*32 + b) << 10) + tid]);
            __syncthreads();
            {
                float a0=0.f,a1=0.f,a2=0.f,a3=0.f;
                const float* ap = aWqT + tid;
                #pragma unroll 4
                for (int k = 0; k < 512; k += 4){
                    a0 += ap[(k+0)*512] * h1s[k+0];
                    a1 += ap[(k+1)*512] * h1s[k+1];
                    a2 += ap[(k+2)*512] * h1s[k+2];
                    a3 += ap[(k+3)*512] * h1s[k+3];
                }
                hqv[tid] = (a0+a1)+(a2+a3);
            }
            __syncthreads();
            {
                const int s = tid >> 2, q = tid & 3;
                const unsigned short* eb = encwb + ((size_t)(b*SS+s))*512 + q*128;
                const float* hq = hqv + q*128;
                const float* vp = v + q*128;
                float p0 = 0.f, p1 = 0.f;
                #pragma unroll 2
                for (int k = 0; k < 128; k += 2){
                    p0 += tanh_f(hq[k]   + b2f(eb[k]))   * vp[k];
                    p1 += tanh_f(hq[k+1] + b2f(eb[k+1])) * vp[k+1];
                }
                float p = p0 + p1;
                p += __shfl_xor(p, 1);
                p += __shfl_xor(p, 2);
                if (q == 0) attv[s] = p;
            }
            __syncthreads();
            float e0 = 0.f, e1 = 0.f;
            if (tid < 64){
                float m2 = fmaxf(attv[tid], attv[tid+64]);
                #pragma unroll
                for (int msk = 32; msk >= 1; msk >>= 1) m2 = fmaxf(m2, __shfl_xor(m2, msk));
                if (tid == 0) rbuf[0] = m2;
            }
            __syncthreads();
            float M = rbuf[0];
            if (tid < 64){
                e0 = __expf(attv[tid] - M);
                e1 = __expf(attv[tid+64] - M);
                float sum = e0 + e1;
                #pragma unroll
                for (int msk = 32; msk >= 1; msk >>= 1) sum += __shfl_xor(sum, msk);
                if (tid == 0) rbuf[1] = sum;
            }
            __syncthreads();
            if (tid < 64){
                float inv = 1.f / rbuf[1];
                attv[tid] = e0*inv; attv[tid+64] = e1*inv;
            }
            __syncthreads();
            {
                float w0=0.f,w1=0.f,w2=0.f,w3=0.f;
                const float* ebase = enc + ((size_t)b*SS)*512 + tid;
                #pragma unroll 4
                for (int s = 0; s < 128; s += 4){
                    w0 += attv[s]   * ebase[(s  )*512];
                    w1 += attv[s+1] * ebase[(s+1)*512];
                    w2 += attv[s+2] * ebase[(s+2)*512];
                    w3 += attv[s+3] * ebase[(s+3)*512];
                }
                catb[((size_t)(ta*32 + b) << 10) + 512 + tid] = f2b((w0+w1)+(w2+w3));
            }
            __syncthreads();
        }
    }
}

// ------------------------------------------------------------------ fc MFMA GEMM + LSE partials
__global__ void __launch_bounds__(256)
k_fc(const float* __restrict__ fcW, const float* __restrict__ fcb, float* __restrict__ ws){
    __shared__ unsigned short As[128*32];
    __shared__ unsigned short Bs[128*32];
    __shared__ float eM[128], eS[128];
    const int tid = threadIdx.x;
    const int mt = blockIdx.x, nt = blockIdx.y;
    const int m0 = mt*128, n0 = nt*128;
    const unsigned short* catb = (const unsigned short*)(ws + OFF_CATB);
    const int lane = tid & 63, wid = tid >> 6;
    const int wr = wid >> 1, wc = wid & 1;
    const int lr = lane & 15, lg = lane >> 4;
    const int ar = tid & 127, ah = tid >> 7;
    const int br = tid >> 1,  bh = tid & 1;
    f32x4 acc[4][4];
    #pragma unroll
    for (int i=0;i<4;i++)
        #pragma unroll
        for (int j=0;j<4;j++) acc[i][j] = (f32x4){0.f,0.f,0.f,0.f};

    for (int kk = 0; kk < 32; ++kk){
        const int k0 = kk*32;
        uint4 a0 = *(const uint4*)(catb + (size_t)(m0+ar)*1024 + k0 + ah*16);
        uint4 a1 = *(const uint4*)(catb + (size_t)(m0+ar)*1024 + k0 + ah*16 + 8);
        const float* bsrc = fcW + (size_t)(n0+br)*1024 + k0 + bh*16;
        float4 f0 = *(const float4*)(bsrc);
        float4 f1 = *(const float4*)(bsrc+4);
        float4 f2 = *(const float4*)(bsrc+8);
        float4 f3 = *(const float4*)(bsrc+12);
        __syncthreads();
        {
            int swz = (ar>>1)&3;
            *(uint4*)&As[ar*32 + ((2*ah  )^swz)*8] = a0;
            *(uint4*)&As[ar*32 + ((2*ah+1)^swz)*8] = a1;
        }
        {
            uint4 p0, p1;
            p0.x = __builtin_amdgcn_perm(__float_as_uint(f0.y), __float_as_uint(f0.x), 0x07060302u);
            p0.y = __builtin_amdgcn_perm(__float_as_uint(f0.w), __float_as_uint(f0.z), 0x07060302u);
            p0.z = __builtin_amdgcn_perm(__float_as_uint(f1.y), __float_as_uint(f1.x), 0x07060302u);
            p0.w = __builtin_amdgcn_perm(__float_as_uint(f1.w), __float_as_uint(f1.z), 0x07060302u);
            p1.x = __builtin_amdgcn_perm(__float_as_uint(f2.y), __float_as_uint(f2.x), 0x07060302u);
            p1.y = __builtin_amdgcn_perm(__float_as_uint(f2.w), __float_as_uint(f2.z), 0x07060302u);
            p1.z = __builtin_amdgcn_perm(__float_as_uint(f3.y), __float_as_uint(f3.x), 0x07060302u);
            p1.w = __builtin_amdgcn_perm(__float_as_uint(f3.w), __float_as_uint(f3.z), 0x07060302u);
            int swz = (br>>1)&3;
            *(uint4*)&Bs[br*32 + ((2*bh  )^swz)*8] = p0;
            *(uint4*)&Bs[br*32 + ((2*bh+1)^swz)*8] = p1;
        }
        __syncthreads();
        short8 av[4], bv[4];
        #pragma unroll
        for (int mi=0; mi<4; ++mi){
            int r = wr*64 + mi*16 + lr;
            av[mi] = *(const short8*)&As[r*32 + ((lg ^ ((r>>1)&3))*8)];
        }
        #pragma unroll
        for (int ni=0; ni<4; ++ni){
            int r = wc*64 + ni*16 + lr;
            bv[ni] = *(const short8*)&Bs[r*32 + ((lg ^ ((r>>1)&3))*8)];
        }
        #pragma unroll
        for (int mi=0; mi<4; ++mi)
            #pragma unroll
            for (int ni=0; ni<4; ++ni)
                acc[mi][ni] = __builtin_amdgcn_mfma_f32_16x16x32_bf16(av[mi], bv[ni], acc[mi][ni], 0, 0, 0);
    }
    float bias[4];
    #pragma unroll
    for (int ni=0; ni<4; ++ni) bias[ni] = fcb[n0 + wc*64 + ni*16 + lr];
    float mxA[4][4], smA[4][4];
    #pragma unroll
    for (int mi=0; mi<4; ++mi){
        #pragma unroll
        for (int reg=0; reg<4; ++reg){
            float mx = -3.4e38f;
            #pragma unroll
            for (int ni=0; ni<4; ++ni) mx = fmaxf(mx, acc[mi][ni][reg] + bias[ni]);
            #pragma unroll
            for (int msk=8; msk>=1; msk>>=1) mx = fmaxf(mx, __shfl_xor(mx, msk));
            float sm = 0.f;
            #pragma unroll
            for (int ni=0; ni<4; ++ni) sm += __expf(acc[mi][ni][reg] + bias[ni] - mx);
            #pragma unroll
            for (int msk=8; msk>=1; msk>>=1) sm += __shfl_xor(sm, msk);
            mxA[mi][reg] = mx; smA[mi][reg] = sm;
            if (wc == 0 && lr == 0){
                int rl = wr*64 + mi*16 + lg*4 + reg;
                eM[rl] = mx; eS[rl] = sm;
            }
        }
    }
    __syncthreads();
    if (wc == 1 && lr == 0){
        float2* part = (float2*)(ws + OFF_PART);
        #pragma unroll
        for (int mi=0; mi<4; ++mi){
            #pragma unroll
            for (int reg=0; reg<4; ++reg){
                int rl = wr*64 + mi*16 + lg*4 + reg;
                float m0v = eM[rl], s0 = eS[rl];
                float m1v = mxA[mi][reg], s1 = smA[mi][reg];
                float M = fmaxf(m0v, m1v);
                float S = s0*__expf(m0v - M) + s1*__expf(m1v - M);
                part[(size_t)(m0 + rl)*NT128 + nt] = make_float2(M, S);
            }
        }
    }
}

// ------------------------------------------- per-row LSE combine + target logit
__global__ void k_row(const int* __restrict__ X, const float* __restrict__ fcW,
                      const float* __restrict__ fcb, float* __restrict__ ws){
    __shared__ float LM[256], LS[256];
    int m = blockIdx.x, tid = threadIdx.x;
    const float2* p = (const float2*)(ws + OFF_PART);
    float M = -3.4e38f, Ssum = 0.f;
    if (tid < NT128){
        float2 q = p[(size_t)m*NT128 + tid];
        M = q.x; Ssum = q.y;
    }
    LM[tid] = M; LS[tid] = Ssum;
    __syncthreads();
    for (int off = 128; off >= 1; off >>= 1){
        if (tid < off){
            float m1 = LM[tid], s1 = LS[tid];
            float m2 = LM[tid+off], s2 = LS[tid+off];
            float mm = fmaxf(m1, m2);
            LM[tid] = mm;
            LS[tid] = s1*__expf(m1-mm) + s2*__expf(m2-mm);
        }
        __syncthreads();
    }
    float lse = LM[0] + __logf(LS[0]);
    __syncthreads();
    int t = m >> 5, b = m & 31;
    int y = X[b*TT + t + 1];
    const unsigned short* cr = (const unsigned short*)(ws + OFF_CATB) + (size_t)m*1024;
    const float* wr = fcW + (size_t)y*1024;
    float a = 0.f;
    #pragma unroll
    for (int k = 0; k < 4; ++k) a += b2f(cr[tid*4+k]) * wr[tid*4+k];
    LM[tid] = a;
    __syncthreads();
    for (int off = 128; off >= 1; off >>= 1){
        if (tid < off) LM[tid] += LM[tid+off];
        __syncthreads();
    }
    if (tid == 0){
        float tl = LM[0] + fcb[y];
        float nll = lse - tl;
        int valid = (y != 0);
        ws[OFF_NLL + m] = valid ? nll : 0.f;
        ws[OFF_CNT + m] = valid ? 1.f : 0.f;
    }
}

// ------------------------------------------------------------------ finalize
__global__ void k_fin(const float* __restrict__ ws, float* __restrict__ out){
    __shared__ float red[256];
    int tid = threadIdx.x;
    float lt = 0.f;
    if (tid < TM1){
        float s = 0.f, c = 0.f;
        for (int b=0;b<NB;b++){
            s += ws[OFF_NLL + tid*NB + b];
            c += ws[OFF_CNT + tid*NB + b];
        }
        lt = s / fmaxf(c, 1.f);
    }
    red[tid] = lt;
    __syncthreads();
    for (int off=128; off>=1; off>>=1){
        if (tid < off) red[tid] += red[tid+off];
        __syncthreads();
    }
    if (tid == 0) out[0] = red[0] / (float)TM1;
}

// -------------------------------------------------------------------- launch
extern "C" void kernel_launch(void* const* d_in, const int* in_sizes, int n_in,
                              void* d_out, int out_size, void* d_ws, size_t ws_size,
                              hipStream_t stream) {
    const int*   X     = (const int*)  d_in[0];
    const float* enc   = (const float*)d_in[1];
    const float* hid   = (const float*)d_in[2];
    const float* cel   = (const float*)d_in[3];
    const float* emb   = (const float*)d_in[4];
    const float* Wih0  = (const float*)d_in[5];
    const float* Whh0  = (const float*)d_in[6];
    const float* bih0  = (const float*)d_in[7];
    const float* bhh0  = (const float*)d_in[8];
    const float* Wih1  = (const float*)d_in[9];
    const float* Whh1  = (const float*)d_in[10];
    const float* bih1  = (const float*)d_in[11];
    const float* bhh1  = (const float*)d_in[12];
    const float* attnW = (const float*)d_in[13];
    const float* attnb = (const float*)d_in[14];
    const float* v     = (const float*)d_in[15];
    const float* fcW   = (const float*)d_in[16];
    const float* fcb   = (const float*)d_in[17];
    float* ws  = (float*)d_ws;
    float* out = (float*)d_out;

    k_init<<<256, 256, 0, stream>>>(hid, cel, ws);
    k_prep<<<1024, 256, 0, stream>>>(attnW, ws);
    k_encw<<<dim3(8,64), 256, 0, stream>>>(enc, attnW, attnb, ws);
    k_g0x<<<dim3(32,64), 256, 0, stream>>>(X, emb, Wih0, bih0, bhh0, ws);

    void* args[] = {(void*)&enc, (void*)&Whh0, (void*)&Wih1, (void*)&Whh1,
                    (void*)&bih1, (void*)&bhh1, (void*)&v, (void*)&ws};
    hipLaunchCooperativeKernel((const void*)k_scan, dim3(NLSTM + 32), dim3(512), args, 0, stream);

    k_fc<<<dim3(32, NT128), 256, 0, stream>>>(fcW, fcb, ws);
    k_row<<<NROWS, 256, 0, stream>>>(X, fcW, fcb, ws);
    k_fin<<<1, 256, 0, stream>>>(ws, out);
}

// Round 5
// 4366.924 us; speedup vs baseline: 2.3235x; 2.3235x over previous
//
#include <hip/hip_runtime.h>
#include <math.h>

#define VOCAB 32000
#define EMB   256
#define HID   512
#define NB    32
#define TT    128
#define TM1   127
#define SS    128
#define NROWS (TM1*NB)     // 4064
#define NT128 250          // 32000/128
#define NLSTM 128          // lstm blocks in scan

// ---- workspace layout (float32 offsets) ----
#define OFF_ENCW 0          // bf16 [32][128][512] enc@attnW_enc^T + attnb
#define OFF_AWQT 1048576    // f32  [512][512]  attnW[:, :512] transposed
#define OFF_H0B  1310720    // bf16 ring [8][32][512] h0
#define OFF_H1B  1376256    // bf16 ring [2][32][512] h1
#define OFF_C0   1392640    // f32  [512][32]
#define OFF_C1   1409024    // f32  [512][32]
#define OFF_G0X  1425408    // bf16 [127][2048][32]  emb@Wih0^T + biases
#define OFF_CATB 5586944    // bf16 [4096][1024]  (h1 history ∥ weighted)
#define OFF_PART 7684096    // float2 [4096][250]; ints [0]=c0 [32]=c1 during scan
#define OFF_NLL  9732096
#define OFF_CNT  9736160

typedef __attribute__((ext_vector_type(8))) short short8;
typedef __attribute__((ext_vector_type(4))) float f32x4;
typedef unsigned long long ull_t;

__device__ __forceinline__ float sigm(float x){ return 1.f/(1.f + __expf(-x)); }
__device__ __forceinline__ float tanh_f(float x){
    x = fminf(fmaxf(x, -15.f), 15.f);
    float e = __expf(2.f*x);
    return (e-1.f)/(e+1.f);
}
__device__ __forceinline__ unsigned short f2b(float f){
    union{float f; unsigned u;} x{f};
    unsigned r = (x.u + 0x7fff + ((x.u>>16)&1)) >> 16;
    return (unsigned short)r;
}
__device__ __forceinline__ float b2f(unsigned short b){
    union{unsigned u; float f;} x{(unsigned)b<<16};
    return x.f;
}
__device__ __forceinline__ uint4 pack8(const float4 f0, const float4 f1){
    uint4 r;
    r.x = ((unsigned)f2b(f0.x)) | ((unsigned)f2b(f0.y)<<16);
    r.y = ((unsigned)f2b(f0.z)) | ((unsigned)f2b(f0.w)<<16);
    r.z = ((unsigned)f2b(f1.x)) | ((unsigned)f2b(f1.y)<<16);
    r.w = ((unsigned)f2b(f1.z)) | ((unsigned)f2b(f1.w)<<16);
    return r;
}
// coherent (L3) 8-byte load/store: no L1/L2 maintenance, always coherence-point
__device__ __forceinline__ ull_t cohl(const ull_t* p){
    return __hip_atomic_load((ull_t*)p, __ATOMIC_RELAXED, __HIP_MEMORY_SCOPE_AGENT);
}
__device__ __forceinline__ void cohs(ull_t* p, ull_t v){
    __hip_atomic_store(p, v, __ATOMIC_RELAXED, __HIP_MEMORY_SCOPE_AGENT);
}
__device__ __forceinline__ short8 cohl16(const unsigned short* p){
    union { ull_t u[2]; short8 s; } a;
    a.u[0] = cohl((const ull_t*)p);
    a.u[1] = cohl((const ull_t*)p + 1);
    return a.s;
}

// ------------------------------------------------------------------ init
__global__ void k_init(const float* __restrict__ hid, const float* __restrict__ cel,
                       float* __restrict__ ws){
    int idx = blockIdx.x*256 + threadIdx.x;
    if (idx < 2*HID*NB){
        int l = idx >> 14, r = idx & 16383;      // r = k*32+b
        int k = r >> 5, b = r & 31;
        float hv = 0.5f*(hid[(2*l)*(NB*HID) + b*HID + k] + hid[(2*l+1)*(NB*HID) + b*HID + k]);
        float cv = 0.5f*(cel[(2*l)*(NB*HID) + b*HID + k] + cel[(2*l+1)*(NB*HID) + b*HID + k]);
        unsigned short* hb = (unsigned short*)(ws + (l==0 ? OFF_H0B : OFF_H1B));
        hb[b*512 + k] = f2b(hv);                 // ring slot 0
        ws[(l==0 ? OFF_C0 : OFF_C1) + k*32 + b] = cv;
    } else {
        int j = idx - 2*HID*NB;
        if (j < 32*1024){                         // zero catb pad rows 4064..4095
            unsigned short* catb = (unsigned short*)(ws + OFF_CATB);
            catb[(size_t)4064*1024 + j] = 0;
        }
        if (j < 2){                               // zero sync counters c0,c1
            ((int*)(ws + OFF_PART))[j*32] = 0;
        }
    }
}

// ------------------------------------------------------------------ prep
__global__ void k_prep(const float* __restrict__ attnW, float* __restrict__ ws){
    int idx = blockIdx.x*256 + threadIdx.x;      // 262144
    int k = idx >> 9, h = idx & 511;
    ws[OFF_AWQT + k*512 + h] = attnW[h*1024 + k];
}

// ---------------------------------------------- encW = enc @ attnW[:,512:]^T + attnb  (bf16)
__global__ void k_encw(const float* __restrict__ enc, const float* __restrict__ attnW,
                       const float* __restrict__ attnb, float* __restrict__ ws){
    __shared__ float As[64][33];
    __shared__ float Bs[64][33];
    int tid = threadIdx.x;
    int nt = blockIdx.x, mt = blockIdx.y;
    int m0 = mt*64, n0 = nt*64;
    int ty = tid >> 4, tx = tid & 15;
    float acc[4][4] = {};
    for (int kk = 0; kk < 16; ++kk){
        int k0 = kk*32;
        #pragma unroll
        for (int i = 0; i < 8; ++i){
            int idx = tid + i*256;
            int r = idx >> 5, k = idx & 31;
            As[r][k] = enc[(m0+r)*HID + k0 + k];
            Bs[r][k] = attnW[(n0+r)*1024 + 512 + k0 + k];
        }
        __syncthreads();
        #pragma unroll
        for (int k = 0; k < 32; ++k){
            float av[4], bv[4];
            #pragma unroll
            for (int i=0;i<4;i++) av[i] = As[ty*4+i][k];
            #pragma unroll
            for (int j=0;j<4;j++) bv[j] = Bs[tx*4+j][k];
            #pragma unroll
            for (int i=0;i<4;i++)
                #pragma unroll
                for (int j=0;j<4;j++) acc[i][j] += av[i]*bv[j];
        }
        __syncthreads();
    }
    unsigned short* encwb = (unsigned short*)(ws + OFF_ENCW);
    #pragma unroll
    for (int i=0;i<4;i++)
      #pragma unroll
      for (int j=0;j<4;j++){
        int m = m0 + ty*4+i, n = n0 + tx*4+j;
        encwb[(size_t)m*512 + n] = f2b(acc[i][j] + attnb[n]);
      }
}

// ------------------------- g0x[t][row][b] = emb[X[b,t]] @ Wih0^T + bih0 + bhh0  (bf16)
__global__ void k_g0x(const int* __restrict__ X, const float* __restrict__ emb,
                      const float* __restrict__ Wih0, const float* __restrict__ bih0,
                      const float* __restrict__ bhh0, float* __restrict__ ws){
    __shared__ float As[64][33];
    __shared__ float Bs[64][33];
    int tid = threadIdx.x;
    int nt = blockIdx.x, mt = blockIdx.y;
    int m0 = mt*64, n0 = nt*64;
    int ty = tid >> 4, tx = tid & 15;
    float acc[4][4] = {};
    for (int kk = 0; kk < 8; ++kk){
        int k0 = kk*32;
        #pragma unroll
        for (int i = 0; i < 8; ++i){
            int idx = tid + i*256;
            int r = idx >> 5, k = idx & 31;
            int m = m0 + r;
            int tok = (m < NROWS) ? X[(m&31)*TT + (m>>5)] : 0;
            As[r][k] = emb[(size_t)tok*EMB + k0 + k];
            Bs[r][k] = Wih0[(n0+r)*EMB + k0 + k];
        }
        __syncthreads();
        #pragma unroll
        for (int k = 0; k < 32; ++k){
            float av[4], bv[4];
            #pragma unroll
            for (int i=0;i<4;i++) av[i] = As[ty*4+i][k];
            #pragma unroll
            for (int j=0;j<4;j++) bv[j] = Bs[tx*4+j][k];
            #pragma unroll
            for (int i=0;i<4;i++)
                #pragma unroll
                for (int j=0;j<4;j++) acc[i][j] += av[i]*bv[j];
        }
        __syncthreads();
    }
    unsigned short* g0xb = (unsigned short*)(ws + OFF_G0X);
    #pragma unroll
    for (int i=0;i<4;i++){
        int m = m0 + ty*4+i;
        if (m >= NROWS) continue;
        int t = m >> 5, b = m & 31;
        #pragma unroll
        for (int j=0;j<4;j++){
            int n = n0 + tx*4+j;
            g0xb[((size_t)t*2048 + n)*32 + b] = f2b(acc[i][j] + bih0[n] + bhh0[n]);
        }
    }
}

// ------------------------------------------------------------------ persistent scan
// 128 lstm blocks (4 units, W0+W1 in LDS) + 32 attn blocks.
// Shared mutable state (h0b/h1b/catb-h1/counters) goes through L3 via relaxed
// agent-scope atomics (sc0 sc1, no L1/L2 maintenance). Read-only data stays cached.
__global__ void __launch_bounds__(512, 1)
k_scan(const float* __restrict__ enc, const float* __restrict__ Whh0,
       const float* __restrict__ Wih1, const float* __restrict__ Whh1,
       const float* __restrict__ bih1, const float* __restrict__ bhh1,
       const float* __restrict__ v, float* ws)
{
    const int blk = blockIdx.x, tid = threadIdx.x;
    __shared__ __align__(16) char smem[59904];
    unsigned short* catb  = (unsigned short*)(ws + OFF_CATB);
    const unsigned short* g0xb  = (const unsigned short*)(ws + OFF_G0X);
    const unsigned short* encwb = (const unsigned short*)(ws + OFF_ENCW);
    unsigned short* h0b = (unsigned short*)(ws + OFF_H0B);   // [8][32][512]
    unsigned short* h1b = (unsigned short*)(ws + OFF_H1B);   // [2][32][512]
    int* c0 = (int*)(ws + OFF_PART);
    int* c1 = (int*)(ws + OFF_PART) + 32;

    if (blk < NLSTM){
        unsigned short* Ws0 = (unsigned short*)smem;              // [16][512]  16 KB
        unsigned short* Ws1 = (unsigned short*)(smem + 16384);    // [16][1024] 32 KB
        float* red  = (float*)(smem + 49152);                     // [8][64][4]  8 KB
        float* gbuf = (float*)(smem + 57344);                     // [32][17]  2176 B
        float* bs1  = (float*)(smem + 59520);                     // [16]
        unsigned short* hstage = (unsigned short*)(smem + 59584); // [32][4]  256 B
        const int u0 = blk*4;
        // ---- stage weights once ----
        if (tid < 256){   // Ws0: rows n = g*4+j of Whh0 (row g*512+u0+j), K=512
            int n = tid >> 4, q = tid & 15;
            int g = n >> 2, j = n & 3;
            const float* src = Whh0 + ((size_t)(g*512 + u0 + j))*512 + q*32;
            #pragma unroll
            for (int c = 0; c < 4; ++c){
                float4 f0 = *(const float4*)(src + c*8);
                float4 f1 = *(const float4*)(src + c*8 + 4);
                int s = q*4 + c;
                *(uint4*)&Ws0[n*512 + ((s ^ (n&7))<<3)] = pack8(f0, f1);
            }
        }
        {   // Ws1: rows n = g*4+j of [Wih1;Whh1] (row g*512+u0+j), K=1024
            int n = tid >> 5, q = tid & 31;
            int g = n >> 2, j = n & 3;
            int grow = g*512 + u0 + j;
            int k0 = q*32;
            const float* src = (k0 < 512) ? (Wih1 + (size_t)grow*512 + k0)
                                          : (Whh1 + (size_t)grow*512 + (k0-512));
            #pragma unroll
            for (int c = 0; c < 4; ++c){
                float4 f0 = *(const float4*)(src + c*8);
                float4 f1 = *(const float4*)(src + c*8 + 4);
                int s = q*4 + c;
                *(uint4*)&Ws1[n*1024 + ((s ^ (n&7))<<3)] = pack8(f0, f1);
            }
        }
        if (tid < 16){
            int g = tid >> 2, j = tid & 3;
            int gr = g*512 + u0 + j;
            bs1[tid] = bih1[gr] + bhh1[gr];
        }
        __syncthreads();

        const int w = tid >> 6, lane = tid & 63;
        const int kg = w & 3, mt = w >> 2;
        const int lr = lane & 15, lg = lane >> 4;

        for (int i = 0; i <= 127; ++i){
            // ---------- part A: lstm0 step i ----------
            if (i <= 126){
                const unsigned short* hsrc = h0b + (i&7)*16384;
                f32x4 acc = {0.f,0.f,0.f,0.f};
                #pragma unroll
                for (int ks = 0; ks < 4; ++ks){
                    int kk = kg*4 + ks;
                    short8 a = cohl16(hsrc + (mt*16+lr)*512 + kk*32 + lg*8);
                    int sl = kk*4 + lg;
                    short8 b0 = *(const short8*)&Ws0[lr*512 + ((sl ^ (lr&7))<<3)];
                    acc = __builtin_amdgcn_mfma_f32_16x16x32_bf16(a, b0, acc, 0,0,0);
                }
                *(f32x4*)&red[(w*64 + lane)*4] = acc;
                __syncthreads();
                {   // combine K-splits: 512 outputs (2mt x 16row x 16b)
                    int reg = tid & 3, ln = (tid>>2) & 63, mtl = tid >> 8;
                    float s = 0.f;
                    #pragma unroll
                    for (int kg2 = 0; kg2 < 4; ++kg2)
                        s += red[((mtl*4+kg2)*64 + ln)*4 + reg];
                    int bb = mtl*16 + (ln>>4)*4 + reg;
                    int nn = ln & 15;
                    gbuf[bb*17 + nn] = s;
                }
                __syncthreads();
                if (tid < 128){
                    int j = tid >> 5, b = tid & 31;
                    int u = u0 + j;
                    const unsigned short* gx = g0xb + (size_t)i*65536;
                    float gi = gbuf[b*17 + 0*4 + j] + b2f(gx[(0*512+u)*32 + b]);
                    float gf = gbuf[b*17 + 1*4 + j] + b2f(gx[(1*512+u)*32 + b]);
                    float gg = gbuf[b*17 + 2*4 + j] + b2f(gx[(2*512+u)*32 + b]);
                    float go = gbuf[b*17 + 3*4 + j] + b2f(gx[(3*512+u)*32 + b]);
                    float c  = ws[OFF_C0 + u*32 + b];
                    float cn = sigm(gf)*c + sigm(gi)*tanh_f(gg);
                    float hn = sigm(go)*tanh_f(cn);
                    ws[OFF_C0 + u*32 + b] = cn;
                    hstage[b*4 + j] = f2b(hn);
                }
                __syncthreads();
                if (tid < 32){
                    ull_t val = *(ull_t*)&hstage[tid*4];
                    cohs((ull_t*)(h0b + ((i+1)&7)*16384 + tid*512 + u0), val);
                }
            }
            // ---------- group barrier (no cache maintenance) ----------
            __syncthreads();      // drains each wave's sc1-stores (vmcnt0) to L3
            if (tid == 0){
                __hip_atomic_fetch_add(c0, 1, __ATOMIC_RELAXED, __HIP_MEMORY_SCOPE_AGENT);
                while (__hip_atomic_load(c0, __ATOMIC_RELAXED, __HIP_MEMORY_SCOPE_AGENT) < NLSTM*(i+1))
                    __builtin_amdgcn_s_sleep(16);
            }
            __syncthreads();
            // ---------- part B: lstm1 step i-1 ----------
            if (i >= 1){
                const unsigned short* h0src = h0b + (i&7)*16384;
                const unsigned short* h1src = h1b + ((i-1)&1)*16384;
                f32x4 acc = {0.f,0.f,0.f,0.f};
                #pragma unroll
                for (int ks = 0; ks < 8; ++ks){
                    int kk = kg*8 + ks;
                    const unsigned short* hs = (kk < 16)
                        ? (h0src + (mt*16+lr)*512 + kk*32 + lg*8)
                        : (h1src + (mt*16+lr)*512 + (kk-16)*32 + lg*8);
                    short8 a = cohl16(hs);
                    int sl = kk*4 + lg;
                    short8 b0 = *(const short8*)&Ws1[lr*1024 + ((sl ^ (lr&7))<<3)];
                    acc = __builtin_amdgcn_mfma_f32_16x16x32_bf16(a, b0, acc, 0,0,0);
                }
                *(f32x4*)&red[(w*64 + lane)*4] = acc;
                __syncthreads();
                {
                    int reg = tid & 3, ln = (tid>>2) & 63, mtl = tid >> 8;
                    float s = 0.f;
                    #pragma unroll
                    for (int kg2 = 0; kg2 < 4; ++kg2)
                        s += red[((mtl*4+kg2)*64 + ln)*4 + reg];
                    int bb = mtl*16 + (ln>>4)*4 + reg;
                    int nn = ln & 15;
                    gbuf[bb*17 + nn] = s;
                }
                __syncthreads();
                if (tid < 128){
                    int j = tid >> 5, b = tid & 31;
                    int u = u0 + j;
                    float gi = gbuf[b*17 + 0*4 + j] + bs1[0*4 + j];
                    float gf = gbuf[b*17 + 1*4 + j] + bs1[1*4 + j];
                    float gg = gbuf[b*17 + 2*4 + j] + bs1[2*4 + j];
                    float go = gbuf[b*17 + 3*4 + j] + bs1[3*4 + j];
                    float c  = ws[OFF_C1 + u*32 + b];
                    float cn = sigm(gf)*c + sigm(gi)*tanh_f(gg);
                    float hn = sigm(go)*tanh_f(cn);
                    ws[OFF_C1 + u*32 + b] = cn;
                    hstage[b*4 + j] = f2b(hn);
                }
                __syncthreads();
                if (tid < 32){
                    ull_t val = *(ull_t*)&hstage[tid*4];
                    cohs((ull_t*)(h1b + (i&1)*16384 + tid*512 + u0), val);
                    cohs((ull_t*)(catb + ((size_t)((i-1)*32 + tid) << 10) + u0), val);
                }
            }
            // ---------- publish h1/catb ----------
            __syncthreads();      // drain sc1-stores before counting
            if (tid == 0)
                __hip_atomic_fetch_add(c1, 1, __ATOMIC_RELAXED, __HIP_MEMORY_SCOPE_AGENT);
        }
    } else {
        // ================= attention: one block per batch =================
        float* h1s  = (float*)smem;           // 512
        float* hqv  = (float*)(smem + 2048);  // 512
        float* attv = (float*)(smem + 4096);  // 128
        float* rbuf = (float*)(smem + 4608);  // 2
        const int b = blk - NLSTM;
        const float* aWqT = ws + OFF_AWQT;
        for (int ta = 0; ta < TM1; ++ta){
            // wait for catb row ta (h1[ta+1]) published at lstm iter ta+1
            if (tid == 0){
                while (__hip_atomic_load(c1, __ATOMIC_RELAXED, __HIP_MEMORY_SCOPE_AGENT) < NLSTM*(ta+2))
                    __builtin_amdgcn_s_sleep(16);
            }
            __syncthreads();
            if (tid < 128){   // coherent read of h1 row (4 bf16 per thread)
                ull_t vq = cohl((const ull_t*)(catb + ((size_t)(ta*32 + b) << 10)) + tid);
                #pragma unroll
                for (int e = 0; e < 4; ++e)
                    h1s[tid*4 + e] = b2f((unsigned short)((vq >> (16*e)) & 0xffff));
            }
            __syncthreads();
            {
                float a0=0.f,a1=0.f,a2=0.f,a3=0.f;
                const float* ap = aWqT + tid;
                #pragma unroll 4
                for (int k = 0; k < 512; k += 4){
                    a0 += ap[(k+0)*512] * h1s[k+0];
                    a1 += ap[(k+1)*512] * h1s[k+1];
                    a2 += ap[(k+2)*512] * h1s[k+2];
                    a3 += ap[(k+3)*512] * h1s[k+3];
                }
                hqv[tid] = (a0+a1)+(a2+a3);
            }
            __syncthreads();
            {
                const int s = tid >> 2, q = tid & 3;
                const unsigned short* eb = encwb + ((size_t)(b*SS+s))*512 + q*128;
                const float* hq = hqv + q*128;
                const float* vp = v + q*128;
                float p0 = 0.f, p1 = 0.f;
                #pragma unroll 2
                for (int k = 0; k < 128; k += 2){
                    p0 += tanh_f(hq[k]   + b2f(eb[k]))   * vp[k];
                    p1 += tanh_f(hq[k+1] + b2f(eb[k+1])) * vp[k+1];
                }
                float p = p0 + p1;
                p += __shfl_xor(p, 1);
                p += __shfl_xor(p, 2);
                if (q == 0) attv[s] = p;
            }
            __syncthreads();
            float e0 = 0.f, e1 = 0.f;
            if (tid < 64){
                float m2 = fmaxf(attv[tid], attv[tid+64]);
                #pragma unroll
                for (int msk = 32; msk >= 1; msk >>= 1) m2 = fmaxf(m2, __shfl_xor(m2, msk));
                if (tid == 0) rbuf[0] = m2;
            }
            __syncthreads();
            float M = rbuf[0];
            if (tid < 64){
                e0 = __expf(attv[tid] - M);
                e1 = __expf(attv[tid+64] - M);
                float sum = e0 + e1;
                #pragma unroll
                for (int msk = 32; msk >= 1; msk >>= 1) sum += __shfl_xor(sum, msk);
                if (tid == 0) rbuf[1] = sum;
            }
            __syncthreads();
            if (tid < 64){
                float inv = 1.f / rbuf[1];
                attv[tid] = e0*inv; attv[tid+64] = e1*inv;
            }
            __syncthreads();
            {
                float w0=0.f,w1=0.f,w2=0.f,w3=0.f;
                const float* ebase = enc + ((size_t)b*SS)*512 + tid;
                #pragma unroll 4
                for (int s = 0; s < 128; s += 4){
                    w0 += attv[s]   * ebase[(s  )*512];
                    w1 += attv[s+1] * ebase[(s+1)*512];
                    w2 += attv[s+2] * ebase[(s+2)*512];
                    w3 += attv[s+3] * ebase[(s+3)*512];
                }
                catb[((size_t)(ta*32 + b) << 10) + 512 + tid] = f2b((w0+w1)+(w2+w3));
            }
            __syncthreads();
        }
    }
}

// ------------------------------------------------------------------ fc MFMA GEMM + LSE partials
__global__ void __launch_bounds__(256)
k_fc(const float* __restrict__ fcW, const float* __restrict__ fcb, float* __restrict__ ws){
    __shared__ unsigned short As[128*32];
    __shared__ unsigned short Bs[128*32];
    __shared__ float eM[128], eS[128];
    const int tid = threadIdx.x;
    const int mt = blockIdx.x, nt = blockIdx.y;
    const int m0 = mt*128, n0 = nt*128;
    const unsigned short* catb = (const unsigned short*)(ws + OFF_CATB);
    const int lane = tid & 63, wid = tid >> 6;
    const int wr = wid >> 1, wc = wid & 1;
    const int lr = lane & 15, lg = lane >> 4;
    const int ar = tid & 127, ah = tid >> 7;
    const int br = tid >> 1,  bh = tid & 1;
    f32x4 acc[4][4];
    #pragma unroll
    for (int i=0;i<4;i++)
        #pragma unroll
        for (int j=0;j<4;j++) acc[i][j] = (f32x4){0.f,0.f,0.f,0.f};

    for (int kk = 0; kk < 32; ++kk){
        const int k0 = kk*32;
        uint4 a0 = *(const uint4*)(catb + (size_t)(m0+ar)*1024 + k0 + ah*16);
        uint4 a1 = *(const uint4*)(catb + (size_t)(m0+ar)*1024 + k0 + ah*16 + 8);
        const float* bsrc = fcW + (size_t)(n0+br)*1024 + k0 + bh*16;
        float4 f0 = *(const float4*)(bsrc);
        float4 f1 = *(const float4*)(bsrc+4);
        float4 f2 = *(const float4*)(bsrc+8);
        float4 f3 = *(const float4*)(bsrc+12);
        __syncthreads();
        {
            int swz = (ar>>1)&3;
            *(uint4*)&As[ar*32 + ((2*ah  )^swz)*8] = a0;
            *(uint4*)&As[ar*32 + ((2*ah+1)^swz)*8] = a1;
        }
        {
            uint4 p0, p1;
            p0.x = __builtin_amdgcn_perm(__float_as_uint(f0.y), __float_as_uint(f0.x), 0x07060302u);
            p0.y = __builtin_amdgcn_perm(__float_as_uint(f0.w), __float_as_uint(f0.z), 0x07060302u);
            p0.z = __builtin_amdgcn_perm(__float_as_uint(f1.y), __float_as_uint(f1.x), 0x07060302u);
            p0.w = __builtin_amdgcn_perm(__float_as_uint(f1.w), __float_as_uint(f1.z), 0x07060302u);
            p1.x = __builtin_amdgcn_perm(__float_as_uint(f2.y), __float_as_uint(f2.x), 0x07060302u);
            p1.y = __builtin_amdgcn_perm(__float_as_uint(f2.w), __float_as_uint(f2.z), 0x07060302u);
            p1.z = __builtin_amdgcn_perm(__float_as_uint(f3.y), __float_as_uint(f3.x), 0x07060302u);
            p1.w = __builtin_amdgcn_perm(__float_as_uint(f3.w), __float_as_uint(f3.z), 0x07060302u);
            int swz = (br>>1)&3;
            *(uint4*)&Bs[br*32 + ((2*bh  )^swz)*8] = p0;
            *(uint4*)&Bs[br*32 + ((2*bh+1)^swz)*8] = p1;
        }
        __syncthreads();
        short8 av[4], bv[4];
        #pragma unroll
        for (int mi=0; mi<4; ++mi){
            int r = wr*64 + mi*16 + lr;
            av[mi] = *(const short8*)&As[r*32 + ((lg ^ ((r>>1)&3))*8)];
        }
        #pragma unroll
        for (int ni=0; ni<4; ++ni){
            int r = wc*64 + ni*16 + lr;
            bv[ni] = *(const short8*)&Bs[r*32 + ((lg ^ ((r>>1)&3))*8)];
        }
        #pragma unroll
        for (int mi=0; mi<4; ++mi)
            #pragma unroll
            for (int ni=0; ni<4; ++ni)
                acc[mi][ni] = __builtin_amdgcn_mfma_f32_16x16x32_bf16(av[mi], bv[ni], acc[mi][ni], 0, 0, 0);
    }
    float bias[4];
    #pragma unroll
    for (int ni=0; ni<4; ++ni) bias[ni] = fcb[n0 + wc*64 + ni*16 + lr];
    float mxA[4][4], smA[4][4];
    #pragma unroll
    for (int mi=0; mi<4; ++mi){
        #pragma unroll
        for (int reg=0; reg<4; ++reg){
            float mx = -3.4e38f;
            #pragma unroll
            for (int ni=0; ni<4; ++ni) mx = fmaxf(mx, acc[mi][ni][reg] + bias[ni]);
            #pragma unroll
            for (int msk=8; msk>=1; msk>>=1) mx = fmaxf(mx, __shfl_xor(mx, msk));
            float sm = 0.f;
            #pragma unroll
            for (int ni=0; ni<4; ++ni) sm += __expf(acc[mi][ni][reg] + bias[ni] - mx);
            #pragma unroll
            for (int msk=8; msk>=1; msk>>=1) sm += __shfl_xor(sm, msk);
            mxA[mi][reg] = mx; smA[mi][reg] = sm;
            if (wc == 0 && lr == 0){
                int rl = wr*64 + mi*16 + lg*4 + reg;
                eM[rl] = mx; eS[rl] = sm;
            }
        }
    }
    __syncthreads();
    if (wc == 1 && lr == 0){
        float2* part = (float2*)(ws + OFF_PART);
        #pragma unroll
        for (int mi=0; mi<4; ++mi){
            #pragma unroll
            for (int reg=0; reg<4; ++reg){
                int rl = wr*64 + mi*16 + lg*4 + reg;
                float m0v = eM[rl], s0 = eS[rl];
                float m1v = mxA[mi][reg], s1 = smA[mi][reg];
                float M = fmaxf(m0v, m1v);
                float S = s0*__expf(m0v - M) + s1*__expf(m1v - M);
                part[(size_t)(m0 + rl)*NT128 + nt] = make_float2(M, S);
            }
        }
    }
}

// ------------------------------------------- per-row LSE combine + target logit
__global__ void k_row(const int* __restrict__ X, const float* __restrict__ fcW,
                      const float* __restrict__ fcb, float* __restrict__ ws){
    __shared__ float LM[256], LS[256];
    int m = blockIdx.x, tid = threadIdx.x;
    const float2* p = (const float2*)(ws + OFF_PART);
    float M = -3.4e38f, Ssum = 0.f;
    if (tid < NT128){
        float2 q = p[(size_t)m*NT128 + tid];
        M = q.x; Ssum = q.y;
    }
    LM[tid] = M; LS[tid] = Ssum;
    __syncthreads();
    for (int off = 128; off >= 1; off >>= 1){
        if (tid < off){
            float m1 = LM[tid], s1 = LS[tid];
            float m2 = LM[tid+off], s2 = LS[tid+off];
            float mm = fmaxf(m1, m2);
            LM[tid] = mm;
            LS[tid] = s1*__expf(m1-mm) + s2*__expf(m2-mm);
        }
        __syncthreads();
    }
    float lse = LM[0] + __logf(LS[0]);
    __syncthreads();
    int t = m >> 5, b = m & 31;
    int y = X[b*TT + t + 1];
    const unsigned short* cr = (const unsigned short*)(ws + OFF_CATB) + (size_t)m*1024;
    const float* wr = fcW + (size_t)y*1024;
    float a = 0.f;
    #pragma unroll
    for (int k = 0; k < 4; ++k) a += b2f(cr[tid*4+k]) * wr[tid*4+k];
    LM[tid] = a;
    __syncthreads();
    for (int off = 128; off >= 1; off >>= 1){
        if (tid < off) LM[tid] += LM[tid+off];
        __syncthreads();
    }
    if (tid == 0){
        float tl = LM[0] + fcb[y];
        float nll = lse - tl;
        int valid = (y != 0);
        ws[OFF_NLL + m] = valid ? nll : 0.f;
        ws[OFF_CNT + m] = valid ? 1.f : 0.f;
    }
}

// ------------------------------------------------------------------ finalize
__global__ void k_fin(const float* __restrict__ ws, float* __restrict__ out){
    __shared__ float red[256];
    int tid = threadIdx.x;
    float lt = 0.f;
    if (tid < TM1){
        float s = 0.f, c = 0.f;
        for (int b=0;b<NB;b++){
            s += ws[OFF_NLL + tid*NB + b];
            c += ws[OFF_CNT + tid*NB + b];
        }
        lt = s / fmaxf(c, 1.f);
    }
    red[tid] = lt;
    __syncthreads();
    for (int off=128; off>=1; off>>=1){
        if (tid < off) red[tid] += red[tid+off];
        __syncthreads();
    }
    if (tid == 0) out[0] = red[0] / (float)TM1;
}

// -------------------------------------------------------------------- launch
extern "C" void kernel_launch(void* const* d_in, const int* in_sizes, int n_in,
                              void* d_out, int out_size, void* d_ws, size_t ws_size,
                              hipStream_t stream) {
    const int*   X     = (const int*)  d_in[0];
    const float* enc   = (const float*)d_in[1];
    const float* hid   = (const float*)d_in[2];
    const float* cel   = (const float*)d_in[3];
    const float* emb   = (const float*)d_in[4];
    const float* Wih0  = (const float*)d_in[5];
    const float* Whh0  = (const float*)d_in[6];
    const float* bih0  = (const float*)d_in[7];
    const float* bhh0  = (const float*)d_in[8];
    const float* Wih1  = (const float*)d_in[9];
    const float* Whh1  = (const float*)d_in[10];
    const float* bih1  = (const float*)d_in[11];
    const float* bhh1  = (const float*)d_in[12];
    const float* attnW = (const float*)d_in[13];
    const float* attnb = (const float*)d_in[14];
    const float* v     = (const float*)d_in[15];
    const float* fcW   = (const float*)d_in[16];
    const float* fcb   = (const float*)d_in[17];
    float* ws  = (float*)d_ws;
    float* out = (float*)d_out;

    k_init<<<256, 256, 0, stream>>>(hid, cel, ws);
    k_prep<<<1024, 256, 0, stream>>>(attnW, ws);
    k_encw<<<dim3(8,64), 256, 0, stream>>>(enc, attnW, attnb, ws);
    k_g0x<<<dim3(32,64), 256, 0, stream>>>(X, emb, Wih0, bih0, bhh0, ws);

    void* args[] = {(void*)&enc, (void*)&Whh0, (void*)&Wih1, (void*)&Whh1,
                    (void*)&bih1, (void*)&bhh1, (void*)&v, (void*)&ws};
    hipLaunchCooperativeKernel((const void*)k_scan, dim3(NLSTM + 32), dim3(512), args, 0, stream);

    k_fc<<<dim3(32, NT128), 256, 0, stream>>>(fcW, fcb, ws);
    k_row<<<NROWS, 256, 0, stream>>>(X, fcW, fcb, ws);
    k_fin<<<1, 256, 0, stream>>>(ws, out);
}

// Round 6
// 4148.075 us; speedup vs baseline: 2.4460x; 1.0528x over previous
//
#include <hip/hip_runtime.h>
#include <math.h>

#define VOCAB 32000
#define EMB   256
#define HID   512
#define NB    32
#define TT    128
#define TM1   127
#define SS    128
#define NROWS (TM1*NB)     // 4064
#define NT128 250          // 32000/128
#define NLSTM 128          // lstm blocks in scan

// ---- workspace layout (float32 offsets) ----
#define OFF_ENCW 0          // bf16 [32][128][512] enc@attnW_enc^T + attnb
#define OFF_AWQT 1048576    // f32  [512][512]  attnW[:, :512] transposed
#define OFF_H0B  1310720    // bf16 ring [8][32][512] h0
#define OFF_H1B  1376256    // bf16 ring [2][32][512] h1
#define OFF_C0   1392640    // f32  [512][32]
#define OFF_C1   1409024    // f32  [512][32]
#define OFF_G0X  1425408    // bf16 [127][2048][32]  emb@Wih0^T + biases
#define OFF_CATB 5586944    // bf16 [4096][1024]  (h1 history ∥ weighted)
#define OFF_PART 7684096    // float2 [4096][250]; during scan: int flags (12288 ints)
#define OFF_NLL  9732096
#define OFF_CNT  9736160

typedef __attribute__((ext_vector_type(8))) short short8;
typedef __attribute__((ext_vector_type(4))) float f32x4;
typedef unsigned long long ull_t;

__device__ __forceinline__ float sigm(float x){ return 1.f/(1.f + __expf(-x)); }
__device__ __forceinline__ float tanh_f(float x){
    x = fminf(fmaxf(x, -15.f), 15.f);
    float e = __expf(2.f*x);
    return (e-1.f)/(e+1.f);
}
__device__ __forceinline__ unsigned short f2b(float f){
    union{float f; unsigned u;} x{f};
    unsigned r = (x.u + 0x7fff + ((x.u>>16)&1)) >> 16;
    return (unsigned short)r;
}
__device__ __forceinline__ float b2f(unsigned short b){
    union{unsigned u; float f;} x{(unsigned)b<<16};
    return x.f;
}
__device__ __forceinline__ uint4 pack8(const float4 f0, const float4 f1){
    uint4 r;
    r.x = ((unsigned)f2b(f0.x)) | ((unsigned)f2b(f0.y)<<16);
    r.y = ((unsigned)f2b(f0.z)) | ((unsigned)f2b(f0.w)<<16);
    r.z = ((unsigned)f2b(f1.x)) | ((unsigned)f2b(f1.y)<<16);
    r.w = ((unsigned)f2b(f1.z)) | ((unsigned)f2b(f1.w)<<16);
    return r;
}
// coherent (L3) accesses: relaxed agent-scope atomics -> sc0 sc1, no L1/L2 maintenance
__device__ __forceinline__ ull_t cohl(const ull_t* p){
    return __hip_atomic_load((ull_t*)p, __ATOMIC_RELAXED, __HIP_MEMORY_SCOPE_AGENT);
}
__device__ __forceinline__ void cohs(ull_t* p, ull_t v){
    __hip_atomic_store(p, v, __ATOMIC_RELAXED, __HIP_MEMORY_SCOPE_AGENT);
}
__device__ __forceinline__ int cohli(const int* p){
    return __hip_atomic_load((int*)p, __ATOMIC_RELAXED, __HIP_MEMORY_SCOPE_AGENT);
}
__device__ __forceinline__ void cohsi(int* p, int v){
    __hip_atomic_store(p, v, __ATOMIC_RELAXED, __HIP_MEMORY_SCOPE_AGENT);
}
__device__ __forceinline__ short8 cohl16(const unsigned short* p){
    union { ull_t u[2]; short8 s; } a;
    a.u[0] = cohl((const ull_t*)p);
    a.u[1] = cohl((const ull_t*)p + 1);
    return a.s;
}

// ------------------------------------------------------------------ init
__global__ void k_init(const float* __restrict__ hid, const float* __restrict__ cel,
                       float* __restrict__ ws){
    int idx = blockIdx.x*256 + threadIdx.x;
    if (idx < 2*HID*NB){
        int l = idx >> 14, r = idx & 16383;      // r = k*32+b
        int k = r >> 5, b = r & 31;
        float hv = 0.5f*(hid[(2*l)*(NB*HID) + b*HID + k] + hid[(2*l+1)*(NB*HID) + b*HID + k]);
        float cv = 0.5f*(cel[(2*l)*(NB*HID) + b*HID + k] + cel[(2*l+1)*(NB*HID) + b*HID + k]);
        unsigned short* hb = (unsigned short*)(ws + (l==0 ? OFF_H0B : OFF_H1B));
        hb[b*512 + k] = f2b(hv);                 // ring slot 0
        ws[(l==0 ? OFF_C0 : OFF_C1) + k*32 + b] = cv;
    } else {
        int j = idx - 2*HID*NB;
        if (j < 32*1024){                         // zero catb pad rows 4064..4095
            unsigned short* catb = (unsigned short*)(ws + OFF_CATB);
            catb[(size_t)4064*1024 + j] = 0;
        }
        if (j < 12288){                           // zero sync flags (arrive1/go1/arrive2)
            ((int*)(ws + OFF_PART))[j] = 0;
        }
    }
}

// ------------------------------------------------------------------ prep
__global__ void k_prep(const float* __restrict__ attnW, float* __restrict__ ws){
    int idx = blockIdx.x*256 + threadIdx.x;      // 262144
    int k = idx >> 9, h = idx & 511;
    ws[OFF_AWQT + k*512 + h] = attnW[h*1024 + k];
}

// ---------------------------------------------- encW = enc @ attnW[:,512:]^T + attnb  (bf16)
__global__ void k_encw(const float* __restrict__ enc, const float* __restrict__ attnW,
                       const float* __restrict__ attnb, float* __restrict__ ws){
    __shared__ float As[64][33];
    __shared__ float Bs[64][33];
    int tid = threadIdx.x;
    int nt = blockIdx.x, mt = blockIdx.y;
    int m0 = mt*64, n0 = nt*64;
    int ty = tid >> 4, tx = tid & 15;
    float acc[4][4] = {};
    for (int kk = 0; kk < 16; ++kk){
        int k0 = kk*32;
        #pragma unroll
        for (int i = 0; i < 8; ++i){
            int idx = tid + i*256;
            int r = idx >> 5, k = idx & 31;
            As[r][k] = enc[(m0+r)*HID + k0 + k];
            Bs[r][k] = attnW[(n0+r)*1024 + 512 + k0 + k];
        }
        __syncthreads();
        #pragma unroll
        for (int k = 0; k < 32; ++k){
            float av[4], bv[4];
            #pragma unroll
            for (int i=0;i<4;i++) av[i] = As[ty*4+i][k];
            #pragma unroll
            for (int j=0;j<4;j++) bv[j] = Bs[tx*4+j][k];
            #pragma unroll
            for (int i=0;i<4;i++)
                #pragma unroll
                for (int j=0;j<4;j++) acc[i][j] += av[i]*bv[j];
        }
        __syncthreads();
    }
    unsigned short* encwb = (unsigned short*)(ws + OFF_ENCW);
    #pragma unroll
    for (int i=0;i<4;i++)
      #pragma unroll
      for (int j=0;j<4;j++){
        int m = m0 + ty*4+i, n = n0 + tx*4+j;
        encwb[(size_t)m*512 + n] = f2b(acc[i][j] + attnb[n]);
      }
}

// ------------------------- g0x[t][row][b] = emb[X[b,t]] @ Wih0^T + bih0 + bhh0  (bf16)
__global__ void k_g0x(const int* __restrict__ X, const float* __restrict__ emb,
                      const float* __restrict__ Wih0, const float* __restrict__ bih0,
                      const float* __restrict__ bhh0, float* __restrict__ ws){
    __shared__ float As[64][33];
    __shared__ float Bs[64][33];
    int tid = threadIdx.x;
    int nt = blockIdx.x, mt = blockIdx.y;
    int m0 = mt*64, n0 = nt*64;
    int ty = tid >> 4, tx = tid & 15;
    float acc[4][4] = {};
    for (int kk = 0; kk < 8; ++kk){
        int k0 = kk*32;
        #pragma unroll
        for (int i = 0; i < 8; ++i){
            int idx = tid + i*256;
            int r = idx >> 5, k = idx & 31;
            int m = m0 + r;
            int tok = (m < NROWS) ? X[(m&31)*TT + (m>>5)] : 0;
            As[r][k] = emb[(size_t)tok*EMB + k0 + k];
            Bs[r][k] = Wih0[(n0+r)*EMB + k0 + k];
        }
        __syncthreads();
        #pragma unroll
        for (int k = 0; k < 32; ++k){
            float av[4], bv[4];
            #pragma unroll
            for (int i=0;i<4;i++) av[i] = As[ty*4+i][k];
            #pragma unroll
            for (int j=0;j<4;j++) bv[j] = Bs[tx*4+j][k];
            #pragma unroll
            for (int i=0;i<4;i++)
                #pragma unroll
                for (int j=0;j<4;j++) acc[i][j] += av[i]*bv[j];
        }
        __syncthreads();
    }
    unsigned short* g0xb = (unsigned short*)(ws + OFF_G0X);
    #pragma unroll
    for (int i=0;i<4;i++){
        int m = m0 + ty*4+i;
        if (m >= NROWS) continue;
        int t = m >> 5, b = m & 31;
        #pragma unroll
        for (int j=0;j<4;j++){
            int n = n0 + tx*4+j;
            g0xb[((size_t)t*2048 + n)*32 + b] = f2b(acc[i][j] + bih0[n] + bhh0[n]);
        }
    }
}

// ------------------------------------------------------------------ persistent scan
// 128 lstm blocks + 32 attn blocks. Distributed-flag sync (one 128B line per
// block): arrive1[blk] -> master (blk0) polls 127 slots in parallel -> go1[blk].
// arrive2[blk] polled directly by each attn block with 128 threads.
__global__ void __launch_bounds__(512, 1)
k_scan(const float* __restrict__ enc, const float* __restrict__ Whh0,
       const float* __restrict__ Wih1, const float* __restrict__ Whh1,
       const float* __restrict__ bih1, const float* __restrict__ bhh1,
       const float* __restrict__ v, float* ws)
{
    const int blk = blockIdx.x, tid = threadIdx.x;
    __shared__ __align__(16) char smem[59904];
    unsigned short* catb  = (unsigned short*)(ws + OFF_CATB);
    const unsigned short* g0xb  = (const unsigned short*)(ws + OFF_G0X);
    const unsigned short* encwb = (const unsigned short*)(ws + OFF_ENCW);
    unsigned short* h0b = (unsigned short*)(ws + OFF_H0B);   // [8][32][512]
    unsigned short* h1b = (unsigned short*)(ws + OFF_H1B);   // [2][32][512]
    int* arr1 = (int*)(ws + OFF_PART);          // [128] stride 32 ints (128B lines)
    int* go1  = arr1 + 4096;                    // [128] stride 32
    int* arr2 = arr1 + 8192;                    // [128] stride 32

    if (blk < NLSTM){
        unsigned short* Ws0 = (unsigned short*)smem;              // [16][512]  16 KB
        unsigned short* Ws1 = (unsigned short*)(smem + 16384);    // [16][1024] 32 KB
        float* red  = (float*)(smem + 49152);                     // [8][64][4]  8 KB
        float* gbuf = (float*)(smem + 57344);                     // [32][17]  2176 B
        float* bs1  = (float*)(smem + 59520);                     // [16]
        unsigned short* hstage = (unsigned short*)(smem + 59584); // [32][4]  256 B
        const int u0 = blk*4;
        // ---- stage weights once ----
        if (tid < 256){   // Ws0: rows n = g*4+j of Whh0 (row g*512+u0+j), K=512
            int n = tid >> 4, q = tid & 15;
            int g = n >> 2, j = n & 3;
            const float* src = Whh0 + ((size_t)(g*512 + u0 + j))*512 + q*32;
            #pragma unroll
            for (int c = 0; c < 4; ++c){
                float4 f0 = *(const float4*)(src + c*8);
                float4 f1 = *(const float4*)(src + c*8 + 4);
                int s = q*4 + c;
                *(uint4*)&Ws0[n*512 + ((s ^ (n&7))<<3)] = pack8(f0, f1);
            }
        }
        {   // Ws1: rows n = g*4+j of [Wih1;Whh1] (row g*512+u0+j), K=1024
            int n = tid >> 5, q = tid & 31;
            int g = n >> 2, j = n & 3;
            int grow = g*512 + u0 + j;
            int k0 = q*32;
            const float* src = (k0 < 512) ? (Wih1 + (size_t)grow*512 + k0)
                                          : (Whh1 + (size_t)grow*512 + (k0-512));
            #pragma unroll
            for (int c = 0; c < 4; ++c){
                float4 f0 = *(const float4*)(src + c*8);
                float4 f1 = *(const float4*)(src + c*8 + 4);
                int s = q*4 + c;
                *(uint4*)&Ws1[n*1024 + ((s ^ (n&7))<<3)] = pack8(f0, f1);
            }
        }
        if (tid < 16){
            int g = tid >> 2, j = tid & 3;
            int gr = g*512 + u0 + j;
            bs1[tid] = bih1[gr] + bhh1[gr];
        }
        __syncthreads();

        const int w = tid >> 6, lane = tid & 63;
        const int kg = w & 3, mt = w >> 2;
        const int lr = lane & 15, lg = lane >> 4;

        for (int i = 0; i <= 127; ++i){
            // ---------- part A: lstm0 step i ----------
            if (i <= 126){
                const unsigned short* hsrc = h0b + (i&7)*16384;
                f32x4 acc = {0.f,0.f,0.f,0.f};
                #pragma unroll
                for (int ks = 0; ks < 4; ++ks){
                    int kk = kg*4 + ks;
                    short8 a = cohl16(hsrc + (mt*16+lr)*512 + kk*32 + lg*8);
                    int sl = kk*4 + lg;
                    short8 b0 = *(const short8*)&Ws0[lr*512 + ((sl ^ (lr&7))<<3)];
                    acc = __builtin_amdgcn_mfma_f32_16x16x32_bf16(a, b0, acc, 0,0,0);
                }
                *(f32x4*)&red[(w*64 + lane)*4] = acc;
                __syncthreads();
                {   // combine K-splits: 512 outputs (2mt x 16row x 16b)
                    int reg = tid & 3, ln = (tid>>2) & 63, mtl = tid >> 8;
                    float s = 0.f;
                    #pragma unroll
                    for (int kg2 = 0; kg2 < 4; ++kg2)
                        s += red[((mtl*4+kg2)*64 + ln)*4 + reg];
                    int bb = mtl*16 + (ln>>4)*4 + reg;
                    int nn = ln & 15;
                    gbuf[bb*17 + nn] = s;
                }
                __syncthreads();
                if (tid < 128){
                    int j = tid >> 5, b = tid & 31;
                    int u = u0 + j;
                    const unsigned short* gx = g0xb + (size_t)i*65536;
                    float gi = gbuf[b*17 + 0*4 + j] + b2f(gx[(0*512+u)*32 + b]);
                    float gf = gbuf[b*17 + 1*4 + j] + b2f(gx[(1*512+u)*32 + b]);
                    float gg = gbuf[b*17 + 2*4 + j] + b2f(gx[(2*512+u)*32 + b]);
                    float go = gbuf[b*17 + 3*4 + j] + b2f(gx[(3*512+u)*32 + b]);
                    float c  = ws[OFF_C0 + u*32 + b];
                    float cn = sigm(gf)*c + sigm(gi)*tanh_f(gg);
                    float hn = sigm(go)*tanh_f(cn);
                    ws[OFF_C0 + u*32 + b] = cn;
                    hstage[b*4 + j] = f2b(hn);
                }
                __syncthreads();
                if (tid < 32){
                    ull_t val = *(ull_t*)&hstage[tid*4];
                    cohs((ull_t*)(h0b + ((i+1)&7)*16384 + tid*512 + u0), val);
                }
            }
            // ---------- distributed barrier (publish h0[i+1]) ----------
            __syncthreads();            // drain all waves' h0 cohs stores
            {
                const int ep = i + 1;
                if (blk == 0){
                    for (;;){
                        int ok = 1;
                        if (tid >= 1 && tid < NLSTM) ok = (cohli(arr1 + tid*32) >= ep);
                        if (__syncthreads_and(ok)) break;
                        __builtin_amdgcn_s_sleep(1);
                    }
                    if (tid >= 1 && tid < NLSTM) cohsi(go1 + tid*32, ep);
                } else {
                    if (tid == 0){
                        cohsi(arr1 + blk*32, ep);
                        while (cohli(go1 + blk*32) < ep) __builtin_amdgcn_s_sleep(4);
                    }
                    __syncthreads();
                }
            }
            // ---------- part B: lstm1 step i-1 ----------
            if (i >= 1){
                const unsigned short* h0src = h0b + (i&7)*16384;
                const unsigned short* h1src = h1b + ((i-1)&1)*16384;
                f32x4 acc = {0.f,0.f,0.f,0.f};
                #pragma unroll
                for (int ks = 0; ks < 8; ++ks){
                    int kk = kg*8 + ks;
                    const unsigned short* hs = (kk < 16)
                        ? (h0src + (mt*16+lr)*512 + kk*32 + lg*8)
                        : (h1src + (mt*16+lr)*512 + (kk-16)*32 + lg*8);
                    short8 a = cohl16(hs);
                    int sl = kk*4 + lg;
                    short8 b0 = *(const short8*)&Ws1[lr*1024 + ((sl ^ (lr&7))<<3)];
                    acc = __builtin_amdgcn_mfma_f32_16x16x32_bf16(a, b0, acc, 0,0,0);
                }
                *(f32x4*)&red[(w*64 + lane)*4] = acc;
                __syncthreads();
                {
                    int reg = tid & 3, ln = (tid>>2) & 63, mtl = tid >> 8;
                    float s = 0.f;
                    #pragma unroll
                    for (int kg2 = 0; kg2 < 4; ++kg2)
                        s += red[((mtl*4+kg2)*64 + ln)*4 + reg];
                    int bb = mtl*16 + (ln>>4)*4 + reg;
                    int nn = ln & 15;
                    gbuf[bb*17 + nn] = s;
                }
                __syncthreads();
                if (tid < 128){
                    int j = tid >> 5, b = tid & 31;
                    int u = u0 + j;
                    float gi = gbuf[b*17 + 0*4 + j] + bs1[0*4 + j];
                    float gf = gbuf[b*17 + 1*4 + j] + bs1[1*4 + j];
                    float gg = gbuf[b*17 + 2*4 + j] + bs1[2*4 + j];
                    float go = gbuf[b*17 + 3*4 + j] + bs1[3*4 + j];
                    float c  = ws[OFF_C1 + u*32 + b];
                    float cn = sigm(gf)*c + sigm(gi)*tanh_f(gg);
                    float hn = sigm(go)*tanh_f(cn);
                    ws[OFF_C1 + u*32 + b] = cn;
                    hstage[b*4 + j] = f2b(hn);
                }
                __syncthreads();
                if (tid < 32){
                    ull_t val = *(ull_t*)&hstage[tid*4];
                    cohs((ull_t*)(h1b + (i&1)*16384 + tid*512 + u0), val);
                    cohs((ull_t*)(catb + ((size_t)((i-1)*32 + tid) << 10) + u0), val);
                }
            }
            // ---------- publish h1/catb for attn ----------
            __syncthreads();            // drain h1/catb cohs stores
            if (tid == 0) cohsi(arr2 + blk*32, i + 1);
        }
    } else {
        // ================= attention: one block per batch =================
        float* h1s  = (float*)smem;           // 512
        float* hqv  = (float*)(smem + 2048);  // 512
        float* attv = (float*)(smem + 4096);  // 128
        float* rbuf = (float*)(smem + 4608);  // 2
        const int b = blk - NLSTM;
        const float* aWqT = ws + OFF_AWQT;
        for (int ta = 0; ta < TM1; ++ta){
            // wait for catb row ta (h1 of step ta, published end of lstm iter ta+1)
            {
                const int ep = ta + 2;
                for (;;){
                    int ok = 1;
                    if (tid < NLSTM) ok = (cohli(arr2 + tid*32) >= ep);
                    if (__syncthreads_and(ok)) break;
                    __builtin_amdgcn_s_sleep(4);
                }
            }
            if (tid < 128){   // coherent read of h1 row (4 bf16 per thread)
                ull_t vq = cohl((const ull_t*)(catb + ((size_t)(ta*32 + b) << 10)) + tid);
                #pragma unroll
                for (int e = 0; e < 4; ++e)
                    h1s[tid*4 + e] = b2f((unsigned short)((vq >> (16*e)) & 0xffff));
            }
            __syncthreads();
            {
                float a0=0.f,a1=0.f,a2=0.f,a3=0.f;
                const float* ap = aWqT + tid;
                #pragma unroll 4
                for (int k = 0; k < 512; k += 4){
                    a0 += ap[(k+0)*512] * h1s[k+0];
                    a1 += ap[(k+1)*512] * h1s[k+1];
                    a2 += ap[(k+2)*512] * h1s[k+2];
                    a3 += ap[(k+3)*512] * h1s[k+3];
                }
                hqv[tid] = (a0+a1)+(a2+a3);
            }
            __syncthreads();
            {
                const int s = tid >> 2, q = tid & 3;
                const unsigned short* eb = encwb + ((size_t)(b*SS+s))*512 + q*128;
                const float* hq = hqv + q*128;
                const float* vp = v + q*128;
                float p0 = 0.f, p1 = 0.f;
                #pragma unroll 2
                for (int k = 0; k < 128; k += 2){
                    p0 += tanh_f(hq[k]   + b2f(eb[k]))   * vp[k];
                    p1 += tanh_f(hq[k+1] + b2f(eb[k+1])) * vp[k+1];
                }
                float p = p0 + p1;
                p += __shfl_xor(p, 1);
                p += __shfl_xor(p, 2);
                if (q == 0) attv[s] = p;
            }
            __syncthreads();
            float e0 = 0.f, e1 = 0.f;
            if (tid < 64){
                float m2 = fmaxf(attv[tid], attv[tid+64]);
                #pragma unroll
                for (int msk = 32; msk >= 1; msk >>= 1) m2 = fmaxf(m2, __shfl_xor(m2, msk));
                if (tid == 0) rbuf[0] = m2;
            }
            __syncthreads();
            float M = rbuf[0];
            if (tid < 64){
                e0 = __expf(attv[tid] - M);
                e1 = __expf(attv[tid+64] - M);
                float sum = e0 + e1;
                #pragma unroll
                for (int msk = 32; msk >= 1; msk >>= 1) sum += __shfl_xor(sum, msk);
                if (tid == 0) rbuf[1] = sum;
            }
            __syncthreads();
            if (tid < 64){
                float inv = 1.f / rbuf[1];
                attv[tid] = e0*inv; attv[tid+64] = e1*inv;
            }
            __syncthreads();
            {
                float w0=0.f,w1=0.f,w2=0.f,w3=0.f;
                const float* ebase = enc + ((size_t)b*SS)*512 + tid;
                #pragma unroll 4
                for (int s = 0; s < 128; s += 4){
                    w0 += attv[s]   * ebase[(s  )*512];
                    w1 += attv[s+1] * ebase[(s+1)*512];
                    w2 += attv[s+2] * ebase[(s+2)*512];
                    w3 += attv[s+3] * ebase[(s+3)*512];
                }
                catb[((size_t)(ta*32 + b) << 10) + 512 + tid] = f2b((w0+w1)+(w2+w3));
            }
            __syncthreads();
        }
    }
}

// ------------------------------------------------------------------ fc MFMA GEMM + LSE partials
__global__ void __launch_bounds__(256)
k_fc(const float* __restrict__ fcW, const float* __restrict__ fcb, float* __restrict__ ws){
    __shared__ unsigned short As[128*32];
    __shared__ unsigned short Bs[128*32];
    __shared__ float eM[128], eS[128];
    const int tid = threadIdx.x;
    const int mt = blockIdx.x, nt = blockIdx.y;
    const int m0 = mt*128, n0 = nt*128;
    const unsigned short* catb = (const unsigned short*)(ws + OFF_CATB);
    const int lane = tid & 63, wid = tid >> 6;
    const int wr = wid >> 1, wc = wid & 1;
    const int lr = lane & 15, lg = lane >> 4;
    const int ar = tid & 127, ah = tid >> 7;
    const int br = tid >> 1,  bh = tid & 1;
    f32x4 acc[4][4];
    #pragma unroll
    for (int i=0;i<4;i++)
        #pragma unroll
        for (int j=0;j<4;j++) acc[i][j] = (f32x4){0.f,0.f,0.f,0.f};

    for (int kk = 0; kk < 32; ++kk){
        const int k0 = kk*32;
        uint4 a0 = *(const uint4*)(catb + (size_t)(m0+ar)*1024 + k0 + ah*16);
        uint4 a1 = *(const uint4*)(catb + (size_t)(m0+ar)*1024 + k0 + ah*16 + 8);
        const float* bsrc = fcW + (size_t)(n0+br)*1024 + k0 + bh*16;
        float4 f0 = *(const float4*)(bsrc);
        float4 f1 = *(const float4*)(bsrc+4);
        float4 f2 = *(const float4*)(bsrc+8);
        float4 f3 = *(const float4*)(bsrc+12);
        __syncthreads();
        {
            int swz = (ar>>1)&3;
            *(uint4*)&As[ar*32 + ((2*ah  )^swz)*8] = a0;
            *(uint4*)&As[ar*32 + ((2*ah+1)^swz)*8] = a1;
        }
        {
            uint4 p0, p1;
            p0.x = __builtin_amdgcn_perm(__float_as_uint(f0.y), __float_as_uint(f0.x), 0x07060302u);
            p0.y = __builtin_amdgcn_perm(__float_as_uint(f0.w), __float_as_uint(f0.z), 0x07060302u);
            p0.z = __builtin_amdgcn_perm(__float_as_uint(f1.y), __float_as_uint(f1.x), 0x07060302u);
            p0.w = __builtin_amdgcn_perm(__float_as_uint(f1.w), __float_as_uint(f1.z), 0x07060302u);
            p1.x = __builtin_amdgcn_perm(__float_as_uint(f2.y), __float_as_uint(f2.x), 0x07060302u);
            p1.y = __builtin_amdgcn_perm(__float_as_uint(f2.w), __float_as_uint(f2.z), 0x07060302u);
            p1.z = __builtin_amdgcn_perm(__float_as_uint(f3.y), __float_as_uint(f3.x), 0x07060302u);
            p1.w = __builtin_amdgcn_perm(__float_as_uint(f3.w), __float_as_uint(f3.z), 0x07060302u);
            int swz = (br>>1)&3;
            *(uint4*)&Bs[br*32 + ((2*bh  )^swz)*8] = p0;
            *(uint4*)&Bs[br*32 + ((2*bh+1)^swz)*8] = p1;
        }
        __syncthreads();
        short8 av[4], bv[4];
        #pragma unroll
        for (int mi=0; mi<4; ++mi){
            int r = wr*64 + mi*16 + lr;
            av[mi] = *(const short8*)&As[r*32 + ((lg ^ ((r>>1)&3))*8)];
        }
        #pragma unroll
        for (int ni=0; ni<4; ++ni){
            int r = wc*64 + ni*16 + lr;
            bv[ni] = *(const short8*)&Bs[r*32 + ((lg ^ ((r>>1)&3))*8)];
        }
        #pragma unroll
        for (int mi=0; mi<4; ++mi)
            #pragma unroll
            for (int ni=0; ni<4; ++ni)
                acc[mi][ni] = __builtin_amdgcn_mfma_f32_16x16x32_bf16(av[mi], bv[ni], acc[mi][ni], 0, 0, 0);
    }
    float bias[4];
    #pragma unroll
    for (int ni=0; ni<4; ++ni) bias[ni] = fcb[n0 + wc*64 + ni*16 + lr];
    float mxA[4][4], smA[4][4];
    #pragma unroll
    for (int mi=0; mi<4; ++mi){
        #pragma unroll
        for (int reg=0; reg<4; ++reg){
            float mx = -3.4e38f;
            #pragma unroll
            for (int ni=0; ni<4; ++ni) mx = fmaxf(mx, acc[mi][ni][reg] + bias[ni]);
            #pragma unroll
            for (int msk=8; msk>=1; msk>>=1) mx = fmaxf(mx, __shfl_xor(mx, msk));
            float sm = 0.f;
            #pragma unroll
            for (int ni=0; ni<4; ++ni) sm += __expf(acc[mi][ni][reg] + bias[ni] - mx);
            #pragma unroll
            for (int msk=8; msk>=1; msk>>=1) sm += __shfl_xor(sm, msk);
            mxA[mi][reg] = mx; smA[mi][reg] = sm;
            if (wc == 0 && lr == 0){
                int rl = wr*64 + mi*16 + lg*4 + reg;
                eM[rl] = mx; eS[rl] = sm;
            }
        }
    }
    __syncthreads();
    if (wc == 1 && lr == 0){
        float2* part = (float2*)(ws + OFF_PART);
        #pragma unroll
        for (int mi=0; mi<4; ++mi){
            #pragma unroll
            for (int reg=0; reg<4; ++reg){
                int rl = wr*64 + mi*16 + lg*4 + reg;
                float m0v = eM[rl], s0 = eS[rl];
                float m1v = mxA[mi][reg], s1 = smA[mi][reg];
                float M = fmaxf(m0v, m1v);
                float S = s0*__expf(m0v - M) + s1*__expf(m1v - M);
                part[(size_t)(m0 + rl)*NT128 + nt] = make_float2(M, S);
            }
        }
    }
}

// ------------------------------------------- per-row LSE combine + target logit
__global__ void k_row(const int* __restrict__ X, const float* __restrict__ fcW,
                      const float* __restrict__ fcb, float* __restrict__ ws){
    __shared__ float LM[256], LS[256];
    int m = blockIdx.x, tid = threadIdx.x;
    const float2* p = (const float2*)(ws + OFF_PART);
    float M = -3.4e38f, Ssum = 0.f;
    if (tid < NT128){
        float2 q = p[(size_t)m*NT128 + tid];
        M = q.x; Ssum = q.y;
    }
    LM[tid] = M; LS[tid] = Ssum;
    __syncthreads();
    for (int off = 128; off >= 1; off >>= 1){
        if (tid < off){
            float m1 = LM[tid], s1 = LS[tid];
            float m2 = LM[tid+off], s2 = LS[tid+off];
            float mm = fmaxf(m1, m2);
            LM[tid] = mm;
            LS[tid] = s1*__expf(m1-mm) + s2*__expf(m2-mm);
        }
        __syncthreads();
    }
    float lse = LM[0] + __logf(LS[0]);
    __syncthreads();
    int t = m >> 5, b = m & 31;
    int y = X[b*TT + t + 1];
    const unsigned short* cr = (const unsigned short*)(ws + OFF_CATB) + (size_t)m*1024;
    const float* wr = fcW + (size_t)y*1024;
    float a = 0.f;
    #pragma unroll
    for (int k = 0; k < 4; ++k) a += b2f(cr[tid*4+k]) * wr[tid*4+k];
    LM[tid] = a;
    __syncthreads();
    for (int off = 128; off >= 1; off >>= 1){
        if (tid < off) LM[tid] += LM[tid+off];
        __syncthreads();
    }
    if (tid == 0){
        float tl = LM[0] + fcb[y];
        float nll = lse - tl;
        int valid = (y != 0);
        ws[OFF_NLL + m] = valid ? nll : 0.f;
        ws[OFF_CNT + m] = valid ? 1.f : 0.f;
    }
}

// ------------------------------------------------------------------ finalize
__global__ void k_fin(const float* __restrict__ ws, float* __restrict__ out){
    __shared__ float red[256];
    int tid = threadIdx.x;
    float lt = 0.f;
    if (tid < TM1){
        float s = 0.f, c = 0.f;
        for (int b=0;b<NB;b++){
            s += ws[OFF_NLL + tid*NB + b];
            c += ws[OFF_CNT + tid*NB + b];
        }
        lt = s / fmaxf(c, 1.f);
    }
    red[tid] = lt;
    __syncthreads();
    for (int off=128; off>=1; off>>=1){
        if (tid < off) red[tid] += red[tid+off];
        __syncthreads();
    }
    if (tid == 0) out[0] = red[0] / (float)TM1;
}

// -------------------------------------------------------------------- launch
extern "C" void kernel_launch(void* const* d_in, const int* in_sizes, int n_in,
                              void* d_out, int out_size, void* d_ws, size_t ws_size,
                              hipStream_t stream) {
    const int*   X     = (const int*)  d_in[0];
    const float* enc   = (const float*)d_in[1];
    const float* hid   = (const float*)d_in[2];
    const float* cel   = (const float*)d_in[3];
    const float* emb   = (const float*)d_in[4];
    const float* Wih0  = (const float*)d_in[5];
    const float* Whh0  = (const float*)d_in[6];
    const float* bih0  = (const float*)d_in[7];
    const float* bhh0  = (const float*)d_in[8];
    const float* Wih1  = (const float*)d_in[9];
    const float* Whh1  = (const float*)d_in[10];
    const float* bih1  = (const float*)d_in[11];
    const float* bhh1  = (const float*)d_in[12];
    const float* attnW = (const float*)d_in[13];
    const float* attnb = (const float*)d_in[14];
    const float* v     = (const float*)d_in[15];
    const float* fcW   = (const float*)d_in[16];
    const float* fcb   = (const float*)d_in[17];
    float* ws  = (float*)d_ws;
    float* out = (float*)d_out;

    k_init<<<256, 256, 0, stream>>>(hid, cel, ws);
    k_prep<<<1024, 256, 0, stream>>>(attnW, ws);
    k_encw<<<dim3(8,64), 256, 0, stream>>>(enc, attnW, attnb, ws);
    k_g0x<<<dim3(32,64), 256, 0, stream>>>(X, emb, Wih0, bih0, bhh0, ws);

    void* args[] = {(void*)&enc, (void*)&Whh0, (void*)&Wih1, (void*)&Whh1,
                    (void*)&bih1, (void*)&bhh1, (void*)&v, (void*)&ws};
    hipLaunchCooperativeKernel((const void*)k_scan, dim3(NLSTM + 32), dim3(512), args, 0, stream);

    k_fc<<<dim3(32, NT128), 256, 0, stream>>>(fcW, fcb, ws);
    k_row<<<NROWS, 256, 0, stream>>>(X, fcW, fcb, ws);
    k_fin<<<1, 256, 0, stream>>>(ws, out);
}